// Round 5
// baseline (4447.097 us; speedup 1.0000x reference)
//
#include <hip/hip_runtime.h>
#include <hip/hip_fp16.h>

#define D 64
constexpr int TPB = 256;             // degZ block size
constexpr int PTPB = 512;            // fuseAB block size
constexpr int STPB = 512;            // spmm block size (8 waves, 16 half-waves)
constexpr int VSHIFT = 7;            // 128 nodes per bucket
constexpr int VNODES = 1 << VSHIFT;  // 128
constexpr int CHUNK = 8192;          // edges per fuseAB block
constexpr int CAP = 4096;            // slack bucket capacity (mean 3413 + ~12 sigma)
constexpr int MAXBUK = 1280;         // LDS bucket-counter capacity (NBUK=1172)
typedef unsigned short u16;

__device__ inline unsigned h2pack(float a, float b) {
    unsigned lo = __half_as_ushort(__float2half_rn(a));
    unsigned hi = __half_as_ushort(__float2half_rn(b));
    return lo | (hi << 16);
}

// ---------------- fuseAB: chunk histogram + global range reservation + place -
// Bucket-partitions the edge list into slack-allocated per-bucket tmp regions.
// No staging of col (second sweep re-reads it; 16KB/block, L1-hot). Within-
// bucket order is arbitrary — the accumulating spmm does not need a sort.
__global__ void fuseAB_kernel(const int* __restrict__ row, const int* __restrict__ col,
                              int* __restrict__ gcnt, unsigned* __restrict__ tmp,
                              int E, int NBUK) {
    __shared__ int h[MAXBUK];        // per-block bucket histogram
    __shared__ int cur[MAXBUK];      // running position within bucket region
    int t = threadIdx.x, blk = blockIdx.x;
    for (int b = t; b < NBUK; b += PTPB) h[b] = 0;
    __syncthreads();
    int base = blk * CHUNK;
    int n = min(CHUNK, E - base);
    for (int i = t; i < n; i += PTPB)
        atomicAdd(&h[col[base + i] >> VSHIFT], 1);
    __syncthreads();
    for (int b = t; b < NBUK; b += PTPB) {
        int c = h[b];
        cur[b] = (c > 0) ? atomicAdd(&gcnt[b], c) : 0;
    }
    __syncthreads();
    for (int i = t; i < n; i += PTPB) {
        int c = col[base + i];               // L1 hit (read in sweep 1)
        int b = c >> VSHIFT;
        int p = atomicAdd(&cur[b], 1);
        if (p < CAP)  // ~12-sigma slack; guard prevents OOB on pathological input
            tmp[(size_t)b * CAP + p] =
                ((unsigned)(c & (VNODES - 1)) << 18) | (unsigned)row[base + i];
    }
}

// ---------------- degZ: per-bucket degree + dis + prescaled fp16 state A -----
// One block per bucket: count local degrees from tmp, emit dis, then write
// A = fp16(dis ⊙ emb) in the PAIRED dim layout: dword j of a node packs
// (dim j, dim j+32) — this makes the spmm LDS atomics bank-conflict-free.
__global__ void degZ_kernel(const unsigned* __restrict__ tmp, const int* __restrict__ gcnt,
                            const float* __restrict__ emb, float* __restrict__ dis,
                            unsigned* __restrict__ A, int N) {
    __shared__ int cnt[VNODES];
    int b = blockIdx.x, t = threadIdx.x;
    if (t < VNODES) cnt[t] = 0;
    __syncthreads();
    int m = min(gcnt[b], CAP);
    const unsigned* __restrict__ tb = tmp + (size_t)b * CAP;
    for (int i = t; i < m; i += TPB)
        atomicAdd(&cnt[tb[i] >> 18], 1);
    __syncthreads();
    int nodeBase = b << VSHIFT;
    if (t < VNODES) {
        int gn = nodeBase + t;
        if (gn < N) {
            int d = cnt[t];
            dis[gn] = (d > 0) ? rsqrtf((float)d) : 0.0f;
        }
    }
    for (int i = t; i < (VNODES << 5); i += TPB) {   // (node, j) pairs
        int n = i >> 5, j = i & 31;
        int gn = nodeBase + n;
        if (gn < N) {
            int d = cnt[n];
            float dv = (d > 0) ? rsqrtf((float)d) : 0.0f;
            float e0 = emb[(size_t)gn * D + j];
            float e1 = emb[(size_t)gn * D + 32 + j];
            A[(size_t)gn * 32 + j] = h2pack(dv * e0, dv * e1);
        }
    }
}

// ---------------- spmm: one bucket per block, fp32 LDS accumulator -----------
// Consumes the UNSORTED bucket-grouped tmp directly (no CSR, no within-bucket
// sort). Per edge: half-wave broadcasts the packed edge, 32 lanes gather the
// 128B pre-scaled source row (dword each = dims (sub, sub+32)), and do two
// bank-conflict-free LDS f32 atomicAdds into acc[localcol][dim]. Tail edges
// go to dummy row VNODES. Epilogue scales by dis[col], accumulates out, and
// writes the pre-scaled next state.
template <int MODE, bool WRITE_DST>
__global__ __launch_bounds__(STPB, 8)
void spmm_kernel(const unsigned* __restrict__ tmp, const int* __restrict__ gcnt,
                 const float* __restrict__ dis,
                 const unsigned* __restrict__ src, unsigned* __restrict__ dst,
                 float4* __restrict__ out4, const float4* __restrict__ emb4,
                 int N) {
    __shared__ float acc[(VNODES + 1) * D];          // 33 KB (incl. dummy row)
    int b = blockIdx.x, t = threadIdx.x;
    for (int i = t; i < (VNODES + 1) * D; i += STPB) acc[i] = 0.0f;
    __syncthreads();
    int m = min(gcnt[b], CAP);
    const unsigned* __restrict__ tb = tmp + (size_t)b * CAP;
    int hw = t >> 5;                 // half-wave 0..15
    int sub = t & 31;                // dim pair (sub, sub+32)
    for (int e0 = hw * 4; e0 < m; e0 += 64) {
        uint4 pk = *(const uint4*)(tb + e0);         // 16B broadcast (aligned)
        #pragma unroll
        for (int j = 0; j < 4; ++j) {
            unsigned p = (j == 0) ? pk.x : (j == 1) ? pk.y : (j == 2) ? pk.z : pk.w;
            int idx = e0 + j;
            int c = (idx < m) ? (int)(p >> 18) : VNODES;     // dummy row on tail
            int r = (idx < m) ? (int)(p & 0x3FFFFu) : 0;
            unsigned u = src[(size_t)r * 32 + sub];          // 128B/row gather
            atomicAdd(&acc[c * D + sub],
                      __half2float(__ushort_as_half((u16)(u & 0xffff))));
            atomicAdd(&acc[c * D + 32 + sub],
                      __half2float(__ushort_as_half((u16)(u >> 16))));
        }
    }
    __syncthreads();
    int nodeBase = b << VSHIFT;
    // out accumulate: (node, float4-group) pairs, canonical dim order
    for (int i = t; i < (VNODES << 4); i += STPB) {
        int n = i >> 4, k = i & 15;
        int gn = nodeBase + n;
        if (gn >= N) continue;
        float dc = dis[gn];
        float4 a = *(const float4*)&acc[n * D + 4 * k];
        float e0 = dc * a.x, e1 = dc * a.y, e2 = dc * a.z, e3 = dc * a.w;
        size_t fo = (size_t)gn * 16 + k;
        float4 c0;
        if (MODE == 0) {
            c0 = emb4[fo];
            c0.x += e0; c0.y += e1; c0.z += e2; c0.w += e3;
        } else if (MODE == 1) {
            c0 = out4[fo];
            c0.x += e0; c0.y += e1; c0.z += e2; c0.w += e3;
        } else {
            c0 = out4[fo];
            c0.x = (c0.x + e0) * 0.25f; c0.y = (c0.y + e1) * 0.25f;
            c0.z = (c0.z + e2) * 0.25f; c0.w = (c0.w + e3) * 0.25f;
        }
        out4[fo] = c0;
    }
    if (WRITE_DST) {                 // pre-scaled next state, paired layout
        for (int i = t; i < (VNODES << 5); i += STPB) {
            int n = i >> 5, j = i & 31;
            int gn = nodeBase + n;
            if (gn >= N) continue;
            float dc = dis[gn];
            float s = dc * dc;       // dis * (dis * acc)
            dst[(size_t)gn * 32 + j] =
                h2pack(s * acc[n * D + j], s * acc[n * D + 32 + j]);
        }
    }
}

extern "C" void kernel_launch(void* const* d_in, const int* in_sizes, int n_in,
                              void* d_out, int out_size, void* d_ws, size_t ws_size,
                              hipStream_t stream) {
    const int* edge = (const int*)d_in[0];
    const float* emb = (const float*)d_in[1];
    const int E = in_sizes[0] / 2;       // 4,000,000
    const int N = in_sizes[1] / D;       // 150,000
    float4* out4 = (float4*)d_out;

    const int* row = edge;
    const int* col = edge + E;

    const int NBLK = (E + CHUNK - 1) / CHUNK;           // 489
    const int NBUK = (N + VNODES - 1) >> VSHIFT;        // 1172

    // workspace layout (~58 MB; no aliasing)
    unsigned* A    = (unsigned*)d_ws;                    // N*32 dwords (fp16 pairs)
    unsigned* B    = A + (size_t)N * 32;                 // N*32 dwords
    unsigned* tmp  = B + (size_t)N * 32;                 // NBUK*CAP dwords (19.2 MB)
    float*    dis  = (float*)(tmp + (size_t)NBUK * CAP); // N floats
    int*      gcnt = (int*)(dis + N);                    // NBUK ints

    // ---- bucket partition + fused degree/dis/prescale
    hipMemsetAsync(gcnt, 0, (size_t)NBUK * sizeof(int), stream);
    fuseAB_kernel<<<NBLK, PTPB, 0, stream>>>(row, col, gcnt, tmp, E, NBUK);
    degZ_kernel<<<NBUK, TPB, 0, stream>>>(tmp, gcnt, emb, dis, A, N);

    // ---- layer 1: out = emb + embs ; B = pre-scaled next state
    spmm_kernel<0, true><<<NBUK, STPB, 0, stream>>>(tmp, gcnt, dis, A, B,
                                                    out4, (const float4*)emb, N);
    // ---- layer 2: out += embs ; A = next state
    spmm_kernel<1, true><<<NBUK, STPB, 0, stream>>>(tmp, gcnt, dis, B, A,
                                                    out4, (const float4*)emb, N);
    // ---- layer 3: out = (out + embs) * 0.25
    spmm_kernel<2, false><<<NBUK, STPB, 0, stream>>>(tmp, gcnt, dis, A, nullptr,
                                                     out4, (const float4*)emb, N);
}

// Round 6
// 445.829 us; speedup vs baseline: 9.9749x; 9.9749x over previous
//
#include <hip/hip_runtime.h>
#include <hip/hip_fp16.h>

#define D 64
constexpr int TPB = 256;             // z0 / spmm block size
constexpr int PTPB = 512;            // fuseAB block size
constexpr int CTPB = 512;            // passC block size
constexpr int VSHIFT = 8;            // 256 nodes per bucket
constexpr int VNODES = 1 << VSHIFT;  // 256
constexpr int CHUNK = 8192;          // edges per fuseAB block
constexpr int CAP = 8192;            // slack bucket capacity (mean 6827 + ~16 sigma)
constexpr int MAXBUK = 640;          // LDS bucket-counter capacity (NBUK=586)
typedef unsigned short u16;

__device__ inline unsigned h2pack(float a, float b) {
    unsigned lo = __half_as_ushort(__float2half_rn(a));
    unsigned hi = __half_as_ushort(__float2half_rn(b));
    return lo | (hi << 16);
}

// ---------------- fuseAB: chunk histogram + global range reservation + place -
// Bucket-partitions the edge list into slack-allocated per-bucket tmp regions.
// One global atomic per (block,bucket) reserves a contiguous range; edge
// placement scatters into ~L2-resident bucket regions. No col staging in LDS
// (second sweep re-reads col, L1/L2-hot) — keeps LDS at 5KB for occupancy
// (round-4 s_col version: 40KB LDS, 17.8% occupancy, 87.7us, latency-bound).
__global__ void fuseAB_kernel(const int* __restrict__ row, const int* __restrict__ col,
                              int* __restrict__ gcnt, unsigned* __restrict__ tmp,
                              int E, int NBUK) {
    __shared__ int h[MAXBUK];        // per-block bucket histogram
    __shared__ int cur[MAXBUK];      // running position within bucket region
    int t = threadIdx.x, blk = blockIdx.x;
    for (int b = t; b < NBUK; b += PTPB) h[b] = 0;
    __syncthreads();
    int base = blk * CHUNK;
    int n = min(CHUNK, E - base);
    for (int i = t; i < n; i += PTPB)
        atomicAdd(&h[col[base + i] >> VSHIFT], 1);
    __syncthreads();
    for (int b = t; b < NBUK; b += PTPB) {
        int c = h[b];
        cur[b] = (c > 0) ? atomicAdd(&gcnt[b], c) : 0;
    }
    __syncthreads();
    for (int i = t; i < n; i += PTPB) {
        int c = col[base + i];               // L1/L2 hit (read in sweep 1)
        int b = c >> VSHIFT;
        int p = atomicAdd(&cur[b], 1);
        if (p < CAP)  // ~16-sigma slack; guard prevents OOB on pathological input
            tmp[(size_t)b * CAP + p] =
                ((unsigned)(c & (VNODES - 1)) << 18) | (unsigned)row[base + i];
    }
}

// ---------------- bscan: exclusive scan of bucket sizes (NBUK <= 1024) -------
__global__ void bscan_kernel(const int* __restrict__ gcnt, int* __restrict__ bExcl, int nb) {
    __shared__ int s[1024];
    int t = threadIdx.x;
    int v = (t < nb) ? gcnt[t] : 0;
    s[t] = v;
    __syncthreads();
    for (int off = 1; off < 1024; off <<= 1) {
        int x = (t >= off) ? s[t - off] : 0;
        __syncthreads();
        s[t] += x;
        __syncthreads();
    }
    if (t < nb) bExcl[t] = s[t] - v;   // exclusive
}

// ---------------- passC: per-bucket counting sort into dense CSR -------------
// One block (512 thr) per bucket of 256 nodes: count local degrees, Blelloch
// scan, place srow; emits row_ptr and dis. 512 threads (vs round-4's 256)
// doubles resident waves — this kernel is latency-bound, ~33MB traffic.
__global__ void passC_kernel(const unsigned* __restrict__ tmp, const int* __restrict__ gcnt,
                             const int* __restrict__ bExcl,
                             int* __restrict__ row_ptr, float* __restrict__ dis,
                             int* __restrict__ srow, int N, int E) {
    __shared__ int cnt[VNODES], sc[VNODES], cur[VNODES];
    int b = blockIdx.x, t = threadIdx.x;
    int nodeBase = b << VSHIFT;
    if (t < VNODES) cnt[t] = 0;
    __syncthreads();
    int m = min(gcnt[b], CAP);
    const unsigned* __restrict__ tb = tmp + (size_t)b * CAP;
    for (int i = t; i < m; i += CTPB)
        atomicAdd(&cnt[tb[i] >> 18], 1);
    __syncthreads();
    if (t < VNODES) sc[t] = cnt[t];
    __syncthreads();
    // Blelloch exclusive scan over 256 counts (extra threads just barrier)
    for (int off = 1; off < VNODES; off <<= 1) {
        int i = (t + 1) * (off << 1) - 1;
        if (i < VNODES) sc[i] += sc[i - off];
        __syncthreads();
    }
    if (t == 0) sc[VNODES - 1] = 0;
    __syncthreads();
    for (int off = VNODES / 2; off >= 1; off >>= 1) {
        int i = (t + 1) * (off << 1) - 1;
        if (i < VNODES) { int x = sc[i - off]; sc[i - off] = sc[i]; sc[i] += x; }
        __syncthreads();
    }
    int gbase = bExcl[b];
    if (t < VNODES) {
        int rp = gbase + sc[t];
        cur[t] = rp;
        int node = nodeBase + t;
        if (node < N) {
            row_ptr[node] = rp;
            int d = cnt[t];
            dis[node] = (d > 0) ? rsqrtf((float)d) : 0.0f;
        }
    }
    if (b == 0 && t == 0) row_ptr[N] = E;
    __syncthreads();
    for (int i = t; i < m; i += CTPB) {
        unsigned pk = tb[i];
        int p = atomicAdd(&cur[pk >> 18], 1);
        srow[p] = (int)(pk & 0x3FFFFu);   // dense-CSR scatter, ~27KB region (L2)
    }
}

// ---------------- z0: A = fp16(dis ⊙ emb); zero row N of A and B -------------
__global__ void z0_kernel(const float4* __restrict__ emb4, const float* __restrict__ dis,
                          unsigned* __restrict__ A, unsigned* __restrict__ B, int N) {
    int total = N * 16;                    // float4 elements (16 per node)
    int stride = gridDim.x * blockDim.x;
    uint2* __restrict__ A2 = (uint2*)A;
    for (int i = blockIdx.x * blockDim.x + threadIdx.x; i < total; i += stride) {
        int node = i >> 4;
        float dv = dis[node];
        float4 x = emb4[i];
        uint2 o;
        o.x = h2pack(dv * x.x, dv * x.y);
        o.y = h2pack(dv * x.z, dv * x.w);
        A2[i] = o;
    }
    if (blockIdx.x == 0 && threadIdx.x < 32) {          // zero-row padding target
        A[(size_t)N * 32 + threadIdx.x] = 0;
        B[(size_t)N * 32 + threadIdx.x] = 0;
    }
}

// ---------------- CSR SpMM: two nodes per wave, dwordx4 fp16x8 gathers -------
// Half-wave h (32 lanes) handles node 2*wave+h. Within a half, 8 lanes cover
// one 128B src row (16B/lane). Invalid tail lanes are redirected to the
// all-zero row at index N, keeping the inner loop branch-free with 8 dwordx4
// loads in flight. (Measured: ~80us/layer, FETCH ~239MB ≈ per-XCD compulsory
// gather bound + streaming — memory-path-bound. Round-5's LDS-accumulator
// variant was 18x WORSE — deep independent load pipeline is essential here.)
#define ACC8(u) do { \
    a0 += __half2float(__ushort_as_half((u16)((u).x & 0xffff))); \
    a1 += __half2float(__ushort_as_half((u16)((u).x >> 16)));    \
    a2 += __half2float(__ushort_as_half((u16)((u).y & 0xffff))); \
    a3 += __half2float(__ushort_as_half((u16)((u).y >> 16)));    \
    a4 += __half2float(__ushort_as_half((u16)((u).z & 0xffff))); \
    a5 += __half2float(__ushort_as_half((u16)((u).z >> 16)));    \
    a6 += __half2float(__ushort_as_half((u16)((u).w & 0xffff))); \
    a7 += __half2float(__ushort_as_half((u16)((u).w >> 16)));    \
} while (0)

template <int MODE, bool WRITE_DST>
__global__ void spmm_kernel(const int* __restrict__ row_ptr, const int* __restrict__ srow,
                            const float* __restrict__ dis,
                            const unsigned* __restrict__ src, unsigned* __restrict__ dst,
                            float2* __restrict__ out2, const float2* __restrict__ emb2,
                            int N) {
    int wave = (blockIdx.x * blockDim.x + threadIdx.x) >> 6;
    int lane = threadIdx.x & 63;
    int half = lane >> 5;
    int sub  = lane & 31;
    int node = 2 * wave + half;
    if (node >= N) return;
    int start = row_ptr[node];
    int end   = row_ptr[node + 1];
    int hb = half << 5;
    int rg = sub >> 3;                 // row-within-group: 0..3
    int q  = sub & 7;                  // 16B slot within row: 0..7
    const uint4* __restrict__ s4 = (const uint4*)src;
    float a0 = 0, a1 = 0, a2 = 0, a3 = 0, a4 = 0, a5 = 0, a6 = 0, a7 = 0;
    for (int base = start; base < end; base += 32) {
        int mye = base + sub;
        int rr = (mye < end) ? srow[mye] : 0;   // 128B coalesced per half
        int cnt = end - base;                   // valid iff (4k+rg) < cnt
        int r0 = __shfl(rr, hb +  0 + rg);
        int r1 = __shfl(rr, hb +  4 + rg);
        int r2 = __shfl(rr, hb +  8 + rg);
        int r3 = __shfl(rr, hb + 12 + rg);
        int r4 = __shfl(rr, hb + 16 + rg);
        int r5 = __shfl(rr, hb + 20 + rg);
        int r6 = __shfl(rr, hb + 24 + rg);
        int r7 = __shfl(rr, hb + 28 + rg);
        r0 = ( 0 + rg < cnt) ? r0 : N;          // zero-row padding
        r1 = ( 4 + rg < cnt) ? r1 : N;
        r2 = ( 8 + rg < cnt) ? r2 : N;
        r3 = (12 + rg < cnt) ? r3 : N;
        r4 = (16 + rg < cnt) ? r4 : N;
        r5 = (20 + rg < cnt) ? r5 : N;
        r6 = (24 + rg < cnt) ? r6 : N;
        r7 = (28 + rg < cnt) ? r7 : N;
        uint4 u0 = s4[(size_t)r0 * 8 + q];      // 8 independent 16B gathers
        uint4 u1 = s4[(size_t)r1 * 8 + q];
        uint4 u2 = s4[(size_t)r2 * 8 + q];
        uint4 u3 = s4[(size_t)r3 * 8 + q];
        uint4 u4 = s4[(size_t)r4 * 8 + q];
        uint4 u5 = s4[(size_t)r5 * 8 + q];
        uint4 u6 = s4[(size_t)r6 * 8 + q];
        uint4 u7 = s4[(size_t)r7 * 8 + q];
        ACC8(u0); ACC8(u1); ACC8(u2); ACC8(u3);
        ACC8(u4); ACC8(u5); ACC8(u6); ACC8(u7);
    }
    // reduce across the 4 row-groups (lane bits 3 and 4; never crosses halves)
    a0 += __shfl_xor(a0, 8);  a1 += __shfl_xor(a1, 8);
    a2 += __shfl_xor(a2, 8);  a3 += __shfl_xor(a3, 8);
    a4 += __shfl_xor(a4, 8);  a5 += __shfl_xor(a5, 8);
    a6 += __shfl_xor(a6, 8);  a7 += __shfl_xor(a7, 8);
    a0 += __shfl_xor(a0, 16); a1 += __shfl_xor(a1, 16);
    a2 += __shfl_xor(a2, 16); a3 += __shfl_xor(a3, 16);
    a4 += __shfl_xor(a4, 16); a5 += __shfl_xor(a5, 16);
    a6 += __shfl_xor(a6, 16); a7 += __shfl_xor(a7, 16);
    if (rg != 0) return;                       // lanes 0..7 of each half finish
    float dc = dis[node];
    float e0 = dc * a0, e1 = dc * a1, e2 = dc * a2, e3 = dc * a3;
    float e4 = dc * a4, e5 = dc * a5, e6 = dc * a6, e7 = dc * a7;
    if (WRITE_DST) {                           // pre-scaled next state (fp16)
        uint4 pk;
        pk.x = h2pack(dc * e0, dc * e1);
        pk.y = h2pack(dc * e2, dc * e3);
        pk.z = h2pack(dc * e4, dc * e5);
        pk.w = h2pack(dc * e6, dc * e7);
        ((uint4*)dst)[(size_t)node * 8 + q] = pk;
    }
    size_t fo = (size_t)node * 16 + q * 2;     // float4 index, dims 8q..8q+7
    float4* __restrict__ o4 = (float4*)out2;
    float4 c0, c1;
    if (MODE == 0) {
        const float4* __restrict__ e4p = (const float4*)emb2;
        c0 = e4p[fo]; c1 = e4p[fo + 1];
        c0.x += e0; c0.y += e1; c0.z += e2; c0.w += e3;
        c1.x += e4; c1.y += e5; c1.z += e6; c1.w += e7;
    } else if (MODE == 1) {
        c0 = o4[fo]; c1 = o4[fo + 1];
        c0.x += e0; c0.y += e1; c0.z += e2; c0.w += e3;
        c1.x += e4; c1.y += e5; c1.z += e6; c1.w += e7;
    } else {
        c0 = o4[fo]; c1 = o4[fo + 1];
        c0.x = (c0.x + e0) * 0.25f; c0.y = (c0.y + e1) * 0.25f;
        c0.z = (c0.z + e2) * 0.25f; c0.w = (c0.w + e3) * 0.25f;
        c1.x = (c1.x + e4) * 0.25f; c1.y = (c1.y + e5) * 0.25f;
        c1.z = (c1.z + e6) * 0.25f; c1.w = (c1.w + e7) * 0.25f;
    }
    o4[fo] = c0; o4[fo + 1] = c1;
}

extern "C" void kernel_launch(void* const* d_in, const int* in_sizes, int n_in,
                              void* d_out, int out_size, void* d_ws, size_t ws_size,
                              hipStream_t stream) {
    const int* edge = (const int*)d_in[0];
    const float* emb = (const float*)d_in[1];
    const int E = in_sizes[0] / 2;       // 4,000,000
    const int N = in_sizes[1] / D;       // 150,000
    float2* out2 = (float2*)d_out;

    const int* row = edge;
    const int* col = edge + E;

    const int NBLK = (E + CHUNK - 1) / CHUNK;           // 489
    const int NBUK = (N + VNODES - 1) >> VSHIFT;        // 586 (<=1024 for bscan)

    // workspace layout (~56 MB). tmp aliases B: tmp is dead (last read in
    // passC) before B is first written (z0's zero-row, then spmm layer 1).
    size_t zrow = (size_t)(N + 1) * 32;                  // dwords per state buf
    size_t tsz  = (size_t)NBUK * CAP;                    // dwords in tmp
    size_t bsz  = (tsz > zrow) ? tsz : zrow;
    unsigned* A       = (unsigned*)d_ws;                 // (N+1)*32 dwords
    unsigned* B       = A + zrow;                        // max(tmp, state) dwords
    unsigned* tmp     = B;                               // alias (see above)
    int*      srow    = (int*)(B + bsz);                 // E ints
    int*      row_ptr = srow + E;                        // N+1 ints
    float*    dis     = (float*)(row_ptr + N + 1);       // N floats
    int*      gcnt    = (int*)(dis + N);                 // NBUK ints
    int*      bExcl   = gcnt + NBUK;                     // NBUK ints

    const int spmm_blocks = (((N + 1) / 2) * 64 + TPB - 1) / TPB;   // 2 nodes/wave

    // ---- bucketed CSR build: fused histogram+reserve+partition, then sort
    hipMemsetAsync(gcnt, 0, (size_t)NBUK * sizeof(int), stream);
    fuseAB_kernel<<<NBLK, PTPB, 0, stream>>>(row, col, gcnt, tmp, E, NBUK);
    bscan_kernel<<<1, 1024, 0, stream>>>(gcnt, bExcl, NBUK);
    passC_kernel<<<NBUK, CTPB, 0, stream>>>(tmp, gcnt, bExcl, row_ptr, dis,
                                            srow, N, E);
    z0_kernel<<<2048, TPB, 0, stream>>>((const float4*)emb, dis, A, B, N);

    // ---- layer 1: out = emb + embs ; B = pre-scaled next state (fp16)
    spmm_kernel<0, true><<<spmm_blocks, TPB, 0, stream>>>(row_ptr, srow, dis, A, B,
                                                          out2, (const float2*)emb, N);
    // ---- layer 2: out += embs ; A = next state
    spmm_kernel<1, true><<<spmm_blocks, TPB, 0, stream>>>(row_ptr, srow, dis, B, A,
                                                          out2, (const float2*)emb, N);
    // ---- layer 3: out = (out + embs) * 0.25
    spmm_kernel<2, false><<<spmm_blocks, TPB, 0, stream>>>(row_ptr, srow, dis, A, nullptr,
                                                           out2, (const float2*)emb, N);
}